// Round 1
// baseline (32.657 us; speedup 1.0000x reference)
//
#include <hip/hip_runtime.h>

// Problem constants (fixed by setup_inputs):
//   B=256, I=512, O=128, K=8, H=O*K=1024
// out[b,o] = 1 - prod_k(1 - Wo[o,k] * prod_i(Wa[i,o,k]*x[b,i] + 1 - Wa[i,o,k]))
// Note gated = 1 + Wa*(x-1), so we precompute xm1 = x-1 and use fmaf(wa, xm1, 1).

#define B_ 256
#define I_ 512
#define O_ 128
#define K_ 8
#define H_ 1024

__device__ __forceinline__ float clamp01(float v) {
    return fminf(fmaxf(v, 0.0f), 1.0f);
}

// Prep: xT[i][b] = x[b][i] - 1  (coalesced writes), and optionally clamped Wa copy.
__global__ __launch_bounds__(256) void dnf_prep(const float* __restrict__ x,
                                                const float* __restrict__ Wa,
                                                float* __restrict__ ws, int mode) {
    float* xT = ws;                       // I_*B_ floats
    float4* WaC = (float4*)(ws + I_ * B_);
    const int tid = blockIdx.x * 256 + threadIdx.x;
    const int nthr = gridDim.x * 256;

    // xT: 131072 elems, idx = i*256 + b
    for (int idx = tid; idx < I_ * B_; idx += nthr) {
        int i = idx >> 8;
        int b = idx & 255;
        xT[idx] = x[b * I_ + i] - 1.0f;
    }
    if (mode >= 2) {
        const float4* src = (const float4*)Wa;
        const int n4 = I_ * H_ / 4;       // 131072 float4s
        for (int idx = tid; idx < n4; idx += nthr) {
            float4 v = src[idx];
            v.x = clamp01(v.x); v.y = clamp01(v.y);
            v.z = clamp01(v.z); v.w = clamp01(v.w);
            WaC[idx] = v;
        }
    }
}

// Main: grid (O_, B_/64). Block = 256 threads = 4 waves.
// Wave w handles i in [w*128, w*128+128); lane = b_local (64 b per b-tile).
// Wa row is wave-uniform per i-step -> broadcast load; xT read coalesced.
template <bool CLAMP_WA>
__global__ __launch_bounds__(256) void dnf_main(const float* __restrict__ xT,
                                                const float* __restrict__ Wa,
                                                const float* __restrict__ Wo,
                                                float* __restrict__ out) {
    const int o = blockIdx.x;                 // 0..127
    const int bt = blockIdx.y;                // 0..3
    const int lane = threadIdx.x & 63;
    const int w = threadIdx.x >> 6;           // 0..3
    const int b = bt * 64 + lane;

    const float* __restrict__ wap = Wa + (size_t)o * K_;
    const float* __restrict__ xp = xT + b;

    float acc[K_];
#pragma unroll
    for (int k = 0; k < K_; ++k) acc[k] = 1.0f;

    const int i0 = w * (I_ / 4);

#pragma unroll 2
    for (int s = 0; s < I_ / 4; ++s) {
        const int i = i0 + s;
        const float* wrow = wap + (size_t)i * H_;
        float4 a0 = *(const float4*)(wrow);
        float4 a1 = *(const float4*)(wrow + 4);
        float xm1 = xp[(size_t)i << 8];       // xT[i][b]
        if (CLAMP_WA) {
            a0.x = clamp01(a0.x); a0.y = clamp01(a0.y);
            a0.z = clamp01(a0.z); a0.w = clamp01(a0.w);
            a1.x = clamp01(a1.x); a1.y = clamp01(a1.y);
            a1.z = clamp01(a1.z); a1.w = clamp01(a1.w);
        }
        acc[0] *= fmaf(a0.x, xm1, 1.0f);
        acc[1] *= fmaf(a0.y, xm1, 1.0f);
        acc[2] *= fmaf(a0.z, xm1, 1.0f);
        acc[3] *= fmaf(a0.w, xm1, 1.0f);
        acc[4] *= fmaf(a1.x, xm1, 1.0f);
        acc[5] *= fmaf(a1.y, xm1, 1.0f);
        acc[6] *= fmaf(a1.z, xm1, 1.0f);
        acc[7] *= fmaf(a1.w, xm1, 1.0f);
    }

    // Combine the 4 waves' partial products, then fuzzy-OR over k.
    __shared__ float red[3][64][K_];          // 6 KB
    if (w > 0) {
#pragma unroll
        for (int k = 0; k < K_; ++k) red[w - 1][lane][k] = acc[k];
    }
    __syncthreads();
    if (w == 0) {
#pragma unroll
        for (int ww = 0; ww < 3; ++ww)
#pragma unroll
            for (int k = 0; k < K_; ++k) acc[k] *= red[ww][lane][k];

        float r = 1.0f;
#pragma unroll
        for (int k = 0; k < K_; ++k) {
            float wo = clamp01(Wo[o * K_ + k]);
            r *= (1.0f - wo * acc[k]);
        }
        out[(size_t)b * O_ + o] = 1.0f - r;
    }
}

// Fallback (tiny/absent workspace): one thread per (b,o).
__global__ __launch_bounds__(256) void dnf_naive(const float* __restrict__ x,
                                                 const float* __restrict__ Wa,
                                                 const float* __restrict__ Wo,
                                                 float* __restrict__ out) {
    const int tid = blockIdx.x * 256 + threadIdx.x;
    if (tid >= B_ * O_) return;
    const int b = tid >> 7;
    const int o = tid & 127;
    float acc[K_];
#pragma unroll
    for (int k = 0; k < K_; ++k) acc[k] = 1.0f;
    for (int i = 0; i < I_; ++i) {
        float xm1 = x[b * I_ + i] - 1.0f;
        const float* wrow = Wa + (size_t)i * H_ + o * K_;
#pragma unroll
        for (int k = 0; k < K_; ++k) {
            float wk = clamp01(wrow[k]);
            acc[k] *= fmaf(wk, xm1, 1.0f);
        }
    }
    float r = 1.0f;
#pragma unroll
    for (int k = 0; k < K_; ++k) {
        float wo = clamp01(Wo[o * K_ + k]);
        r *= (1.0f - wo * acc[k]);
    }
    out[(size_t)b * O_ + o] = 1.0f - r;
}

extern "C" void kernel_launch(void* const* d_in, const int* in_sizes, int n_in,
                              void* d_out, int out_size, void* d_ws, size_t ws_size,
                              hipStream_t stream) {
    const float* x  = (const float*)d_in[0];   // (B, I, 1)
    const float* Wa = (const float*)d_in[1];   // (I, H)
    const float* Wo = (const float*)d_in[2];   // (H, 1)
    float* out = (float*)d_out;                // (B, O)
    float* ws = (float*)d_ws;

    const size_t need_xT = (size_t)I_ * B_ * sizeof(float);          // 512 KB
    const size_t need_all = need_xT + (size_t)I_ * H_ * sizeof(float); // +2 MB

    if (ws_size >= need_all) {
        dnf_prep<<<512, 256, 0, stream>>>(x, Wa, ws, 2);
        dnf_main<false><<<dim3(O_, B_ / 64), 256, 0, stream>>>(ws, ws + I_ * B_, Wo, out);
    } else if (ws_size >= need_xT) {
        dnf_prep<<<512, 256, 0, stream>>>(x, Wa, ws, 1);
        dnf_main<true><<<dim3(O_, B_ / 64), 256, 0, stream>>>(ws, Wa, Wo, out);
    } else {
        dnf_naive<<<(B_ * O_ + 255) / 256, 256, 0, stream>>>(x, Wa, Wo, out);
    }
}

// Round 2
// 28.517 us; speedup vs baseline: 1.1452x; 1.1452x over previous
//
#include <hip/hip_runtime.h>

// Problem constants (fixed by setup_inputs):
//   B=256, I=512, O=128, K=8, H=O*K=1024
// out[b,o] = 1 - prod_k(1 - Wo[o,k] * prod_i(Wa[i,o,k]*x[b,i] + 1 - Wa[i,o,k]))
// gated = 1 + Wa*(x-1)  ->  precompute xm1 = x-1, inner op = fmaf(wa, xm1, 1).

#define B_ 256
#define I_ 512
#define O_ 128
#define K_ 8
#define H_ 1024

__device__ __forceinline__ float clamp01(float v) {
    return fminf(fmaxf(v, 0.0f), 1.0f);
}

// Prep: xT[i][b] = x[b][i] - 1 (coalesced writes), plus clamped Wa copy.
// Total traffic ~9 MB, all L2-scale; ~1-2 us.
__global__ __launch_bounds__(256) void dnf_prep(const float* __restrict__ x,
                                                const float* __restrict__ Wa,
                                                float* __restrict__ ws, int mode) {
    float* xT = ws;                       // I_*B_ floats
    float4* WaC = (float4*)(ws + I_ * B_);
    const int tid = blockIdx.x * 256 + threadIdx.x;
    const int nthr = gridDim.x * 256;

    for (int idx = tid; idx < I_ * B_; idx += nthr) {
        int i = idx >> 8;
        int b = idx & 255;
        xT[idx] = x[b * I_ + i] - 1.0f;
    }
    if (mode >= 2) {
        const float4* src = (const float4*)Wa;
        const int n4 = I_ * H_ / 4;
        for (int idx = tid; idx < n4; idx += nthr) {
            float4 v = src[idx];
            v.x = clamp01(v.x); v.y = clamp01(v.y);
            v.z = clamp01(v.z); v.w = clamp01(v.w);
            WaC[idx] = v;
        }
    }
}

// Main: grid (O_, B_/64). Block = 512 threads = 8 waves.
// Wave w handles i in [w*64, w*64+64); lane = b_local.
// Wa row is wave-uniform per i-step (s_load broadcast); xT read coalesced.
// 4096 waves total -> 4 waves/SIMD for latency hiding.
template <bool CLAMP_WA>
__global__ __launch_bounds__(512) void dnf_main(const float* __restrict__ xT,
                                                const float* __restrict__ Wa,
                                                const float* __restrict__ Wo,
                                                float* __restrict__ out) {
    const int o = blockIdx.x;                 // 0..127
    const int bt = blockIdx.y;                // 0..3
    const int lane = threadIdx.x & 63;
    const int w = threadIdx.x >> 6;           // 0..7
    const int b = bt * 64 + lane;

    const float* __restrict__ wap = Wa + (size_t)o * K_;
    const float* __restrict__ xp = xT + b;

    float acc[K_];
#pragma unroll
    for (int k = 0; k < K_; ++k) acc[k] = 1.0f;

    const int i0 = w * (I_ / 8);

#pragma unroll 4
    for (int s = 0; s < I_ / 8; ++s) {
        const int i = i0 + s;
        const float* wrow = wap + (size_t)i * H_;
        float4 a0 = *(const float4*)(wrow);
        float4 a1 = *(const float4*)(wrow + 4);
        float xm1 = xp[(size_t)i << 8];       // xT[i][b]
        if (CLAMP_WA) {
            a0.x = clamp01(a0.x); a0.y = clamp01(a0.y);
            a0.z = clamp01(a0.z); a0.w = clamp01(a0.w);
            a1.x = clamp01(a1.x); a1.y = clamp01(a1.y);
            a1.z = clamp01(a1.z); a1.w = clamp01(a1.w);
        }
        acc[0] *= fmaf(a0.x, xm1, 1.0f);
        acc[1] *= fmaf(a0.y, xm1, 1.0f);
        acc[2] *= fmaf(a0.z, xm1, 1.0f);
        acc[3] *= fmaf(a0.w, xm1, 1.0f);
        acc[4] *= fmaf(a1.x, xm1, 1.0f);
        acc[5] *= fmaf(a1.y, xm1, 1.0f);
        acc[6] *= fmaf(a1.z, xm1, 1.0f);
        acc[7] *= fmaf(a1.w, xm1, 1.0f);
    }

    // Combine the 8 waves' partial products, then fuzzy-OR over k.
    __shared__ float red[7][64][K_];          // 14 KB
    if (w > 0) {
#pragma unroll
        for (int k = 0; k < K_; ++k) red[w - 1][lane][k] = acc[k];
    }
    __syncthreads();
    if (w == 0) {
#pragma unroll
        for (int ww = 0; ww < 7; ++ww)
#pragma unroll
            for (int k = 0; k < K_; ++k) acc[k] *= red[ww][lane][k];

        float r = 1.0f;
#pragma unroll
        for (int k = 0; k < K_; ++k) {
            float wo = clamp01(Wo[o * K_ + k]);
            r *= (1.0f - wo * acc[k]);
        }
        out[(size_t)b * O_ + o] = 1.0f - r;
    }
}

// Fallback (tiny/absent workspace): one thread per (b,o).
__global__ __launch_bounds__(256) void dnf_naive(const float* __restrict__ x,
                                                 const float* __restrict__ Wa,
                                                 const float* __restrict__ Wo,
                                                 float* __restrict__ out) {
    const int tid = blockIdx.x * 256 + threadIdx.x;
    if (tid >= B_ * O_) return;
    const int b = tid >> 7;
    const int o = tid & 127;
    float acc[K_];
#pragma unroll
    for (int k = 0; k < K_; ++k) acc[k] = 1.0f;
    for (int i = 0; i < I_; ++i) {
        float xm1 = x[b * I_ + i] - 1.0f;
        const float* wrow = Wa + (size_t)i * H_ + o * K_;
#pragma unroll
        for (int k = 0; k < K_; ++k) {
            float wk = clamp01(wrow[k]);
            acc[k] *= fmaf(wk, xm1, 1.0f);
        }
    }
    float r = 1.0f;
#pragma unroll
    for (int k = 0; k < K_; ++k) {
        float wo = clamp01(Wo[o * K_ + k]);
        r *= (1.0f - wo * acc[k]);
    }
    out[(size_t)b * O_ + o] = 1.0f - r;
}

extern "C" void kernel_launch(void* const* d_in, const int* in_sizes, int n_in,
                              void* d_out, int out_size, void* d_ws, size_t ws_size,
                              hipStream_t stream) {
    const float* x  = (const float*)d_in[0];   // (B, I, 1)
    const float* Wa = (const float*)d_in[1];   // (I, H)
    const float* Wo = (const float*)d_in[2];   // (H, 1)
    float* out = (float*)d_out;                // (B, O)
    float* ws = (float*)d_ws;

    const size_t need_xT = (size_t)I_ * B_ * sizeof(float);            // 512 KB
    const size_t need_all = need_xT + (size_t)I_ * H_ * sizeof(float); // +2 MB

    if (ws_size >= need_all) {
        dnf_prep<<<512, 256, 0, stream>>>(x, Wa, ws, 2);
        dnf_main<false><<<dim3(O_, B_ / 64), 512, 0, stream>>>(ws, ws + I_ * B_, Wo, out);
    } else if (ws_size >= need_xT) {
        dnf_prep<<<512, 256, 0, stream>>>(x, Wa, ws, 1);
        dnf_main<true><<<dim3(O_, B_ / 64), 512, 0, stream>>>(ws, Wa, Wo, out);
    } else {
        dnf_naive<<<(B_ * O_ + 255) / 256, 256, 0, stream>>>(x, Wa, Wo, out);
    }
}

// Round 3
// 14.324 us; speedup vs baseline: 2.2799x; 1.9909x over previous
//
#include <hip/hip_runtime.h>

// DNF network: B=256, I=512, O=128, K=8, H=O*K=1024
// out[b,o] = 1 - prod_k(1 - Wo[o,k] * prod_i(Wa[i,o*K+k]*x[b,i] + 1 - Wa[i,o*K+k]))
// gate = 1 + Wa*(x-1)  ->  stage xm1 = x-1 in LDS, inner op = fmaf(wa, xm1, 1).
//
// Single fused kernel (no workspace, 1 graph node):
//   lane  = h within a 64-wide h-tile (h = o*8+k)  -> Wa loads coalesced 256B/wave
//   block = (h-tile, b-group of 8) ; 8 waves = 8 i-segments of 64
//   xm1 for the block's 8 batch rows staged once in LDS (16 KB), read as
//   uniform-address ds_read_b128 broadcasts (conflict-free).
//   i-segment partial products combined via LDS; fuzzy-OR over k via
//   __shfl_xor within 8-lane groups.

#define B_ 256
#define I_ 512
#define O_ 128
#define K_ 8
#define H_ 1024
#define NB 8          // batch rows per block
#define SW 8          // i-segment waves per block

__global__ __launch_bounds__(512) void dnf_fused(const float* __restrict__ x,
                                                 const float* __restrict__ Wa,
                                                 const float* __restrict__ Wo,
                                                 float* __restrict__ out) {
    __shared__ float xm1[I_][NB];            // 16 KB, [i][b]
    __shared__ float red[SW - 1][64][NB];    // 14 KB

    const int tid  = threadIdx.x;
    const int lane = tid & 63;
    const int w    = tid >> 6;               // 0..7 = i-segment
    const int ht   = blockIdx.x;             // 0..15 h-tile
    const int bg   = blockIdx.y;             // 0..31 b-group
    const int h    = ht * 64 + lane;
    const int b0   = bg * NB;

    // Stage xm1[i][b] = x[b0+b][i] - 1. Thread t owns row i = t.
    // Per wave, fixed b: 64 consecutive floats -> coalesced.
    {
        const float* xp = x + (size_t)b0 * I_ + tid;
        float v[NB];
#pragma unroll
        for (int b = 0; b < NB; ++b) v[b] = xp[(size_t)b * I_] - 1.0f;
#pragma unroll
        for (int b = 0; b < NB; ++b) xm1[tid][b] = v[b];
    }
    __syncthreads();

    float acc[NB];
#pragma unroll
    for (int b = 0; b < NB; ++b) acc[b] = 1.0f;

    const int i0 = w * (I_ / SW);
    const float* __restrict__ wp = Wa + (size_t)i0 * H_ + h;

#pragma unroll 4
    for (int s = 0; s < I_ / SW; ++s) {
        float wa = __builtin_amdgcn_fmed3f(wp[(size_t)s * H_], 0.0f, 1.0f);
        const float4* xr = (const float4*)&xm1[i0 + s][0];
        float4 u0 = xr[0];
        float4 u1 = xr[1];
        acc[0] *= fmaf(wa, u0.x, 1.0f);
        acc[1] *= fmaf(wa, u0.y, 1.0f);
        acc[2] *= fmaf(wa, u0.z, 1.0f);
        acc[3] *= fmaf(wa, u0.w, 1.0f);
        acc[4] *= fmaf(wa, u1.x, 1.0f);
        acc[5] *= fmaf(wa, u1.y, 1.0f);
        acc[6] *= fmaf(wa, u1.z, 1.0f);
        acc[7] *= fmaf(wa, u1.w, 1.0f);
    }

    // Combine the 8 i-segment partial products per (h, b).
    if (w > 0) {
        float4* r = (float4*)&red[w - 1][lane][0];
        r[0] = make_float4(acc[0], acc[1], acc[2], acc[3]);
        r[1] = make_float4(acc[4], acc[5], acc[6], acc[7]);
    }
    __syncthreads();

    if (w == 0) {
#pragma unroll
        for (int ww = 0; ww < SW - 1; ++ww) {
            const float4* r = (const float4*)&red[ww][lane][0];
            float4 p0 = r[0];
            float4 p1 = r[1];
            acc[0] *= p0.x; acc[1] *= p0.y; acc[2] *= p0.z; acc[3] *= p0.w;
            acc[4] *= p1.x; acc[5] *= p1.y; acc[6] *= p1.z; acc[7] *= p1.w;
        }

        // Fuzzy OR over k: lane = o_local*8 + k, reduce within 8-lane groups.
        const float wo = __builtin_amdgcn_fmed3f(Wo[h], 0.0f, 1.0f);
        const int og = ht * 8 + (lane >> 3);
        float outv[NB];
#pragma unroll
        for (int b = 0; b < NB; ++b) {
            float t = fmaf(-wo, acc[b], 1.0f);   // 1 - wo*and
            t *= __shfl_xor(t, 1);
            t *= __shfl_xor(t, 2);
            t *= __shfl_xor(t, 4);
            outv[b] = 1.0f - t;
        }
        if ((lane & 7) == 0) {
#pragma unroll
            for (int b = 0; b < NB; ++b)
                out[(size_t)(b0 + b) * O_ + og] = outv[b];
        }
    }
}

extern "C" void kernel_launch(void* const* d_in, const int* in_sizes, int n_in,
                              void* d_out, int out_size, void* d_ws, size_t ws_size,
                              hipStream_t stream) {
    const float* x  = (const float*)d_in[0];   // (B, I, 1)
    const float* Wa = (const float*)d_in[1];   // (I, H)
    const float* Wo = (const float*)d_in[2];   // (H, 1)
    float* out = (float*)d_out;                // (B, O)
    (void)d_ws; (void)ws_size; (void)in_sizes; (void)n_in; (void)out_size;

    dnf_fused<<<dim3(H_ / 64, B_ / NB), 512, 0, stream>>>(x, Wa, Wo, out);
}